// Round 9
// baseline (346.342 us; speedup 1.0000x reference)
//
#include <hip/hip_runtime.h>
#include <hip/hip_bf16.h>

// GraphSAGE 3-layer forward. SPLIT structure.
// CSR build (compressed preamble) -> per layer: aggregate kernel + MFMA GEMM.
//   aggregate: gather bf16 HI-plane rows; one wave = 4 nodes, quarter-wave x
//     uint4 = full 256B row; 8-deep chunks; fp32 mean; emit hi/lo planes.
//   GEMM (R9): 64x128 tile. A staged via global_load_lds, double-buffered
//     (2 x 8KB LDS), one barrier per K-step. B fragments loaded DIRECTLY
//     global->register (B = 128KB, L2-resident, shared by all blocks) —
//     removes 2/3 of the vmcnt drain mass and 32KB of LDS vs R8.
//   Layer-2 (fout<=64) slim mode: 4 waves x 16 rows x 48 cols (3 c-tiles).

#define THREADS 256

typedef unsigned short u16;
typedef __attribute__((ext_vector_type(8))) short bf16x8;
typedef __attribute__((ext_vector_type(4))) float f32x4;

__device__ inline u16 f2bf(float f) {
    union { float f; unsigned u; } v; v.f = f;
    unsigned r = (v.u + 0x7FFFu + ((v.u >> 16) & 1u)) >> 16;
    return (u16)r;
}
__device__ inline float bf2f(u16 b) {
    union { unsigned u; float f; } v; v.u = ((unsigned)b) << 16;
    return v.f;
}
__device__ inline unsigned pack2(float a, float b) {
    return (unsigned)f2bf(a) | ((unsigned)f2bf(b) << 16);
}

#define GLDS16(gp, lp)                                                         \
    __builtin_amdgcn_global_load_lds(                                          \
        (const __attribute__((address_space(1))) void*)(gp),                   \
        (__attribute__((address_space(3))) void*)(lp), 16, 0, 0)

// ---------------- preamble: deg-count + prepX + prepW3 in one kernel ----------------
__global__ void k_preamble(const float* __restrict__ x, u16* __restrict__ hi,
                           u16* __restrict__ lo, int n32,
                           const int* __restrict__ dst, int* __restrict__ deg, int E,
                           const float* __restrict__ Ws0, const float* __restrict__ Wn0,
                           const float* __restrict__ Ws1, const float* __restrict__ Wn1,
                           const float* __restrict__ Ws2, const float* __restrict__ Wn2,
                           u16* __restrict__ Bt) {
    int idx = blockIdx.x * blockDim.x + threadIdx.x;
    // prepX: over n*32 float4s
    if (idx < n32) {
        float4 v = ((const float4*)x)[idx];
        float h0 = bf2f(f2bf(v.x)), h1 = bf2f(f2bf(v.y)), h2 = bf2f(f2bf(v.z)), h3 = bf2f(f2bf(v.w));
        uint2 hp, lp;
        hp.x = pack2(h0, h1); hp.y = pack2(h2, h3);
        lp.x = pack2(v.x - h0, v.y - h1); lp.y = pack2(v.z - h2, v.w - h3);
        ((uint2*)hi)[idx] = hp;
        ((uint2*)lo)[idx] = lp;
    }
    // degree count
    if (idx < E) atomicAdd(&deg[dst[idx]], 1);
    // prepW3: all 3 layers' W -> Bt hi/lo planes [layer][hi|lo][128*256]
    if (idx < 3 * 128 * 256) {
        int layer = idx >> 15;
        int within = idx & 32767;
        int col = within >> 8;
        int k = within & 255;
        const float* Ws = (layer == 0) ? Ws0 : (layer == 1) ? Ws1 : Ws2;
        const float* Wn = (layer == 0) ? Wn0 : (layer == 1) ? Wn1 : Wn2;
        int fout = (layer == 2) ? 47 : 128;
        float v = 0.f;
        if (col < fout) v = (k < 128) ? Ws[k * fout + col] : Wn[(k - 128) * fout + col];
        u16 h = f2bf(v);
        Bt[layer * 65536 + within] = h;
        Bt[layer * 65536 + 32768 + within] = f2bf(v - bf2f(h));
    }
}

// ---------------- CSR build ----------------
__global__ void k_scan_block(const int* __restrict__ deg, int* __restrict__ off,
                             int* __restrict__ bsum, int n) {
    __shared__ int s[256];
    int t = threadIdx.x;
    int base = blockIdx.x * 1024 + t * 4;
    int v[4];
#pragma unroll
    for (int i = 0; i < 4; i++) v[i] = (base + i < n) ? deg[base + i] : 0;
    int sum = v[0] + v[1] + v[2] + v[3];
    int val = sum;
    s[t] = val;
    __syncthreads();
    for (int o = 1; o < 256; o <<= 1) {
        int x = (t >= o) ? s[t - o] : 0;
        __syncthreads();
        val += x;
        s[t] = val;
        __syncthreads();
    }
    int run = val - sum;
#pragma unroll
    for (int i = 0; i < 4; i++) {
        if (base + i < n) off[base + i] = run;
        run += v[i];
    }
    if (t == 255) bsum[blockIdx.x] = val;
}

// scan_add with INLINE bsum prefix: first wave strided-sums bsum[0..blockIdx).
__global__ void k_scan_add(int* __restrict__ off, const int* __restrict__ bsum, int n) {
    __shared__ int sAdd;
    int t = threadIdx.x;
    if (t < 64) {
        int v = 0;
        for (int i = t; i < blockIdx.x; i += 64) v += bsum[i];
#pragma unroll
        for (int o = 32; o; o >>= 1) v += __shfl_xor(v, o, 64);
        if (t == 0) sAdd = v;
    }
    __syncthreads();
    int add = sAdd;
    int base = blockIdx.x * 1024 + t * 4;
#pragma unroll
    for (int i = 0; i < 4; i++)
        if (base + i < n) off[base + i] += add;
}

// claims slots directly on off: after this kernel off[d] = end pointer.
__global__ void k_fill(const int* __restrict__ src, const int* __restrict__ dst,
                       int* __restrict__ off, int* __restrict__ eidx, int E) {
    int e = blockIdx.x * blockDim.x + threadIdx.x;
    if (e < E) {
        int d = dst[e];
        int p = atomicAdd(&off[d], 1);
        eidx[p] = src[e];
    }
}

// ---------------- aggregation ----------------
// one wave = 4 nodes; quarter-wave (16 lanes) x uint4 (8 feats, 16B) = full
// 256B row per quarter. 8-deep masked chunks. fp32 accumulate.
// off[] holds END pointers (post-fill): base = off[node] - cnt.
__global__ void k_aggregate(const u16* __restrict__ hi_in, const int* __restrict__ eidx,
                            const int* __restrict__ off, const int* __restrict__ deg,
                            u16* __restrict__ mhi, u16* __restrict__ mlo, int n) {
    int wv = blockIdx.x * 4 + (threadIdx.x >> 6);
    int lane = threadIdx.x & 63;
    int quarter = lane >> 4;
    int ql = lane & 15;
    int node = wv * 4 + quarter;
    if (node >= n) return;
    int cnt = deg[node];
    int base = off[node] - cnt;
    const uint4* h4 = (const uint4*)hi_in;  // row = 16 uint4
    float acc[8];
#pragma unroll
    for (int i = 0; i < 8; i++) acc[i] = 0.f;
    for (int j = 0; j < cnt; j += 8) {
        int s[8];
        float m[8];
#pragma unroll
        for (int u = 0; u < 8; u++) {
            int jj = j + u;
            s[u] = eidx[base + (jj < cnt ? jj : 0)];
            m[u] = (jj < cnt) ? 1.f : 0.f;
        }
        uint4 v[8];
#pragma unroll
        for (int u = 0; u < 8; u++) v[u] = h4[(size_t)s[u] * 16 + ql];
#pragma unroll
        for (int u = 0; u < 8; u++) {
            acc[0] = fmaf(m[u], bf2f((u16)(v[u].x & 0xffffu)), acc[0]);
            acc[1] = fmaf(m[u], bf2f((u16)(v[u].x >> 16)), acc[1]);
            acc[2] = fmaf(m[u], bf2f((u16)(v[u].y & 0xffffu)), acc[2]);
            acc[3] = fmaf(m[u], bf2f((u16)(v[u].y >> 16)), acc[3]);
            acc[4] = fmaf(m[u], bf2f((u16)(v[u].z & 0xffffu)), acc[4]);
            acc[5] = fmaf(m[u], bf2f((u16)(v[u].z >> 16)), acc[5]);
            acc[6] = fmaf(m[u], bf2f((u16)(v[u].w & 0xffffu)), acc[6]);
            acc[7] = fmaf(m[u], bf2f((u16)(v[u].w >> 16)), acc[7]);
        }
    }
    float iv = 1.0f / (float)(cnt > 1 ? cnt : 1);
    float a[8], r[8];
#pragma unroll
    for (int i = 0; i < 8; i++) {
        a[i] = acc[i] * iv;
        r[i] = bf2f(f2bf(a[i]));
    }
    uint4 hp, lp;
    hp.x = pack2(a[0], a[1]); hp.y = pack2(a[2], a[3]);
    hp.z = pack2(a[4], a[5]); hp.w = pack2(a[6], a[7]);
    lp.x = pack2(a[0] - r[0], a[1] - r[1]); lp.y = pack2(a[2] - r[2], a[3] - r[3]);
    lp.z = pack2(a[4] - r[4], a[5] - r[5]); lp.w = pack2(a[6] - r[6], a[7] - r[7]);
    ((uint4*)mhi)[(size_t)node * 16 + ql] = hp;
    ((uint4*)mlo)[(size_t)node * 16 + ql] = lp;
}

// ---------------- MFMA GEMM (bf16x3 split), 64x128 tile ----------------
// A: staged global_load_lds, double-buffered (2 x 8KB), swizzled (rule #21).
// B: fragments loaded DIRECTLY global->register (L2-resident 128KB operand).
// One __syncthreads per K-step: at the barrier, buf b (staged last step, a
// full ds_read+MFMA phase ago) is drained; reads of b^1 are complete.
// fout>64 : 2x2 waves, 64 rows x 128 cols. fout<=64: slim, 4 strips x 48 cols.
__global__ __launch_bounds__(256) void k_gemm_mfma(
    const u16* __restrict__ Ahi_s, const u16* __restrict__ Alo_s,
    const u16* __restrict__ Ahi_n, const u16* __restrict__ Alo_n,
    const u16* __restrict__ Bthi, const u16* __restrict__ Btlo,
    const float* __restrict__ bias, float* __restrict__ out_f32,
    u16* __restrict__ out_hi, u16* __restrict__ out_lo, int n, int fout, int relu) {
    __shared__ u16 smem[2 * 4096];  // per buffer: A hi [0,2048) | A lo [2048,4096)

    int t = threadIdx.x;
    int w = t >> 6;
    int lane = t & 63;
    int wr = w >> 1, wc = w & 1;
    size_t row0 = (size_t)blockIdx.x * 64;

    const bool slim = (fout <= 64);
    const int rbase = slim ? (w * 16) : (wr * 32);
    const int nR = slim ? 1 : 2;
    const int nC = slim ? 3 : 4;
    const int cbase = slim ? 0 : (wc * 64);

    f32x4 acc[2][4];
#pragma unroll
    for (int r = 0; r < 2; r++)
#pragma unroll
        for (int c = 0; c < 4; c++) acc[r][c] = (f32x4){0.f, 0.f, 0.f, 0.f};

    int fr = lane & 15;
    int q = lane >> 4;

    // A staging addresses (per thread, constant across K-steps except kk)
    int sr = t >> 2;      // A row 0..63
    int ss = t & 3;       // slot
    int sgA = ss ^ ((sr >> 1) & 3);

#define STAGEA(ks_, b_)                                                         \
    {                                                                           \
        int kk_ = (ks_) * 32;                                                   \
        const u16* Phi_ = (kk_ < 128) ? Ahi_s : Ahi_n;                          \
        const u16* Plo_ = (kk_ < 128) ? Alo_s : Alo_n;                          \
        int kc_ = kk_ & 127;                                                    \
        GLDS16(Phi_ + (row0 + sr) * 128 + kc_ + sgA * 8,                        \
               &smem[(b_) * 4096 + sr * 32 + ss * 8]);                          \
        GLDS16(Plo_ + (row0 + sr) * 128 + kc_ + sgA * 8,                        \
               &smem[(b_) * 4096 + 2048 + sr * 32 + ss * 8]);                   \
    }

    STAGEA(0, 0);
    for (int ks = 0; ks < 8; ks++) {
        int b = ks & 1;
        int kk = ks * 32;
        __syncthreads();  // drains buf b's staging (issued one full phase ago)
        if (ks < 7) STAGEA(ks + 1, b ^ 1);

        // B fragments: direct global->register, L2-hit (same elements as the
        // staged path: B[col][kk + q*8 .. +8])
        bf16x8 b_hi[4], b_lo[4];
#pragma unroll
        for (int c = 0; c < 4; c++) {
            if (c >= nC) continue;
            int col = cbase + c * 16 + fr;
            size_t bo = (size_t)col * 256 + kk + q * 8;
            b_hi[c] = *(const bf16x8*)&Bthi[bo];
            b_lo[c] = *(const bf16x8*)&Btlo[bo];
        }

        bf16x8 a_hi[2], a_lo[2];
#pragma unroll
        for (int r = 0; r < 2; r++) {
            if (r >= nR) continue;
            int row = rbase + r * 16 + fr;
            int ad = b * 4096 + row * 32 + ((q ^ ((row >> 1) & 3)) << 3);
            a_hi[r] = *(const bf16x8*)&smem[ad];
            a_lo[r] = *(const bf16x8*)&smem[ad + 2048];
        }
#pragma unroll
        for (int r = 0; r < 2; r++) {
            if (r >= nR) continue;
#pragma unroll
            for (int c = 0; c < 4; c++) {
                if (c >= nC) continue;
                acc[r][c] = __builtin_amdgcn_mfma_f32_16x16x32_bf16(
                    a_hi[r], b_hi[c], acc[r][c], 0, 0, 0);
                acc[r][c] = __builtin_amdgcn_mfma_f32_16x16x32_bf16(
                    a_hi[r], b_lo[c], acc[r][c], 0, 0, 0);
                acc[r][c] = __builtin_amdgcn_mfma_f32_16x16x32_bf16(
                    a_lo[r], b_hi[c], acc[r][c], 0, 0, 0);
            }
        }
    }
#undef STAGEA

    // epilogue: C/D layout col=lane&15, row=quad*4+reg
    int quad = lane >> 4;
    int lcol = lane & 15;
#pragma unroll
    for (int r = 0; r < 2; r++) {
        if (r >= nR) continue;
#pragma unroll
        for (int c = 0; c < 4; c++) {
            if (c >= nC) continue;
            int col = cbase + c * 16 + lcol;
            float bv = (col < fout) ? bias[col] : 0.f;
#pragma unroll
            for (int g = 0; g < 4; g++) {
                size_t row = row0 + rbase + r * 16 + quad * 4 + g;
                if (row >= (size_t)n || col >= fout) continue;
                float v = acc[r][c][g] + bv;
                if (relu) v = v > 0.f ? v : 0.f;
                if (out_f32) out_f32[row * fout + col] = v;
                if (out_hi) {
                    u16 h = f2bf(v);
                    out_hi[row * 128 + col] = h;
                    out_lo[row * 128 + col] = f2bf(v - bf2f(h));
                }
            }
        }
    }
}

extern "C" void kernel_launch(void* const* d_in, const int* in_sizes, int n_in,
                              void* d_out, int out_size, void* d_ws, size_t ws_size,
                              hipStream_t stream) {
    const float* x = (const float*)d_in[0];
    const int* src = (const int*)d_in[1];
    const int* dst = (const int*)d_in[2];
    const float* Ws0 = (const float*)d_in[3];
    const float* Wn0 = (const float*)d_in[4];
    const float* b0 = (const float*)d_in[5];
    const float* Ws1 = (const float*)d_in[6];
    const float* Wn1 = (const float*)d_in[7];
    const float* b1 = (const float*)d_in[8];
    const float* Ws2 = (const float*)d_in[9];
    const float* Wn2 = (const float*)d_in[10];
    const float* b2 = (const float*)d_in[11];
    float* out = (float*)d_out;

    const int N = in_sizes[0] / 128;
    const int E = in_sizes[1];
    const int Npad = ((N + 63) / 64) * 64;

    // ---- workspace layout (bytes) ----
    char* p = (char*)d_ws;
    u16* P0hi = (u16*)p; p += (size_t)Npad * 128 * 2;  // x planes, then h1 planes
    u16* P0lo = (u16*)p; p += (size_t)Npad * 128 * 2;
    u16* P1hi = (u16*)p; p += (size_t)Npad * 128 * 2;  // h0 planes
    u16* P1lo = (u16*)p; p += (size_t)Npad * 128 * 2;
    u16* Mhi = (u16*)p; p += (size_t)Npad * 128 * 2;   // msum planes
    u16* Mlo = (u16*)p; p += (size_t)Npad * 128 * 2;
    u16* Bt = (u16*)p; p += 3 * 2 * 128 * 256 * 2;     // [layer][hi|lo][32768]
    int* deg = (int*)p; p += (size_t)N * 4;
    int* off = (int*)p; p += (size_t)N * 4;
    int* eidx = (int*)p; p += (size_t)E * 4;
    int* bsum = (int*)p;

    const int nPX = N * 32;  // float4s in x
    int nPre = nPX;
    if (E > nPre) nPre = E;
    if (3 * 128 * 256 > nPre) nPre = 3 * 128 * 256;
    const int nbPre = (nPre + THREADS - 1) / THREADS;
    const int nbE = (E + THREADS - 1) / THREADS;
    const int nbScan = (N + 1023) / 1024;
    const int nbAgg = (N + 15) / 16;                   // 4 waves x 4 nodes per block
    const int nbGemm = (N + 63) / 64;

    hipMemsetAsync(deg, 0, (size_t)N * sizeof(int), stream);

    k_preamble<<<nbPre, THREADS, 0, stream>>>(x, P0hi, P0lo, nPX, dst, deg, E,
                                              Ws0, Wn0, Ws1, Wn1, Ws2, Wn2, Bt);
    k_scan_block<<<nbScan, 256, 0, stream>>>(deg, off, bsum, N);
    k_scan_add<<<nbScan, 256, 0, stream>>>(off, bsum, N);
    k_fill<<<nbE, THREADS, 0, stream>>>(src, dst, off, eidx, E);

    // layer 0: x planes -> h0 planes (P1)
    k_aggregate<<<nbAgg, 256, 0, stream>>>(P0hi, eidx, off, deg, Mhi, Mlo, N);
    k_gemm_mfma<<<nbGemm, 256, 0, stream>>>(P0hi, P0lo, Mhi, Mlo,
                                            Bt + 0 * 65536, Bt + 0 * 65536 + 32768, b0,
                                            (float*)nullptr, P1hi, P1lo, N, 128, 1);
    // layer 1: h0 planes -> h1 planes (reuse P0)
    k_aggregate<<<nbAgg, 256, 0, stream>>>(P1hi, eidx, off, deg, Mhi, Mlo, N);
    k_gemm_mfma<<<nbGemm, 256, 0, stream>>>(P1hi, P1lo, Mhi, Mlo,
                                            Bt + 1 * 65536, Bt + 1 * 65536 + 32768, b1,
                                            (float*)nullptr, P0hi, P0lo, N, 128, 1);
    // layer 2: h1 planes -> out (C=47, fp32, no relu) — slim GEMM mode
    k_aggregate<<<nbAgg, 256, 0, stream>>>(P0hi, eidx, off, deg, Mhi, Mlo, N);
    k_gemm_mfma<<<nbGemm, 256, 0, stream>>>(P0hi, P0lo, Mhi, Mlo,
                                            Bt + 2 * 65536, Bt + 2 * 65536 + 32768, b2,
                                            out, (u16*)nullptr, (u16*)nullptr, N, 47, 0);
}

// Round 10
// 297.822 us; speedup vs baseline: 1.1629x; 1.1629x over previous
//
#include <hip/hip_runtime.h>
#include <hip/hip_bf16.h>

// GraphSAGE 3-layer forward. SPLIT structure (best-replicated: R5/R7 ~299us).
// CSR build (compressed preamble) -> per layer: aggregate kernel + MFMA GEMM.
//   aggregate: gather bf16 HI-plane rows; one wave = 4 nodes, quarter-wave x
//     uint4 = full 256B row; 8-deep chunks; fp32 mean; emit hi/lo planes.
//   GEMM: 64x128 tile (782 blocks ~3/CU), bf16x3 split, K=256, single-buffer
//     staging (R8 dbuf and R9 B-direct both regressed — latency/TLP-bound).
//     Frag-read bank fix (rule #21): linear LDS dest for global_load_lds,
//     source slot pre-swizzled sg = s ^ ((row>>1)&3), ds_read same XOR.
//   Layer-2 (fout<=64) slim mode: 4 waves x 16 rows x 48 cols (3 c-tiles).
//   cur[] removed — k_fill claims slots via atomicAdd on off (end-ptr);
//   aggregates use base = off[node] - cnt.

#define THREADS 256

typedef unsigned short u16;
typedef __attribute__((ext_vector_type(8))) short bf16x8;
typedef __attribute__((ext_vector_type(4))) float f32x4;

__device__ inline u16 f2bf(float f) {
    union { float f; unsigned u; } v; v.f = f;
    unsigned r = (v.u + 0x7FFFu + ((v.u >> 16) & 1u)) >> 16;
    return (u16)r;
}
__device__ inline float bf2f(u16 b) {
    union { unsigned u; float f; } v; v.u = ((unsigned)b) << 16;
    return v.f;
}
__device__ inline unsigned pack2(float a, float b) {
    return (unsigned)f2bf(a) | ((unsigned)f2bf(b) << 16);
}

#define GLDS16(gp, lp)                                                         \
    __builtin_amdgcn_global_load_lds(                                          \
        (const __attribute__((address_space(1))) void*)(gp),                   \
        (__attribute__((address_space(3))) void*)(lp), 16, 0, 0)

// ---------------- preamble: deg-count + prepX + prepW3 in one kernel ----------------
__global__ void k_preamble(const float* __restrict__ x, u16* __restrict__ hi,
                           u16* __restrict__ lo, int n32,
                           const int* __restrict__ dst, int* __restrict__ deg, int E,
                           const float* __restrict__ Ws0, const float* __restrict__ Wn0,
                           const float* __restrict__ Ws1, const float* __restrict__ Wn1,
                           const float* __restrict__ Ws2, const float* __restrict__ Wn2,
                           u16* __restrict__ Bt) {
    int idx = blockIdx.x * blockDim.x + threadIdx.x;
    // prepX: over n*32 float4s
    if (idx < n32) {
        float4 v = ((const float4*)x)[idx];
        float h0 = bf2f(f2bf(v.x)), h1 = bf2f(f2bf(v.y)), h2 = bf2f(f2bf(v.z)), h3 = bf2f(f2bf(v.w));
        uint2 hp, lp;
        hp.x = pack2(h0, h1); hp.y = pack2(h2, h3);
        lp.x = pack2(v.x - h0, v.y - h1); lp.y = pack2(v.z - h2, v.w - h3);
        ((uint2*)hi)[idx] = hp;
        ((uint2*)lo)[idx] = lp;
    }
    // degree count
    if (idx < E) atomicAdd(&deg[dst[idx]], 1);
    // prepW3: all 3 layers' W -> Bt hi/lo planes [layer][hi|lo][128*256]
    if (idx < 3 * 128 * 256) {
        int layer = idx >> 15;
        int within = idx & 32767;
        int col = within >> 8;
        int k = within & 255;
        const float* Ws = (layer == 0) ? Ws0 : (layer == 1) ? Ws1 : Ws2;
        const float* Wn = (layer == 0) ? Wn0 : (layer == 1) ? Wn1 : Wn2;
        int fout = (layer == 2) ? 47 : 128;
        float v = 0.f;
        if (col < fout) v = (k < 128) ? Ws[k * fout + col] : Wn[(k - 128) * fout + col];
        u16 h = f2bf(v);
        Bt[layer * 65536 + within] = h;
        Bt[layer * 65536 + 32768 + within] = f2bf(v - bf2f(h));
    }
}

// ---------------- CSR build ----------------
__global__ void k_scan_block(const int* __restrict__ deg, int* __restrict__ off,
                             int* __restrict__ bsum, int n) {
    __shared__ int s[256];
    int t = threadIdx.x;
    int base = blockIdx.x * 1024 + t * 4;
    int v[4];
#pragma unroll
    for (int i = 0; i < 4; i++) v[i] = (base + i < n) ? deg[base + i] : 0;
    int sum = v[0] + v[1] + v[2] + v[3];
    int val = sum;
    s[t] = val;
    __syncthreads();
    for (int o = 1; o < 256; o <<= 1) {
        int x = (t >= o) ? s[t - o] : 0;
        __syncthreads();
        val += x;
        s[t] = val;
        __syncthreads();
    }
    int run = val - sum;
#pragma unroll
    for (int i = 0; i < 4; i++) {
        if (base + i < n) off[base + i] = run;
        run += v[i];
    }
    if (t == 255) bsum[blockIdx.x] = val;
}

// scan_add with INLINE bsum prefix: first wave strided-sums bsum[0..blockIdx).
__global__ void k_scan_add(int* __restrict__ off, const int* __restrict__ bsum, int n) {
    __shared__ int sAdd;
    int t = threadIdx.x;
    if (t < 64) {
        int v = 0;
        for (int i = t; i < blockIdx.x; i += 64) v += bsum[i];
#pragma unroll
        for (int o = 32; o; o >>= 1) v += __shfl_xor(v, o, 64);
        if (t == 0) sAdd = v;
    }
    __syncthreads();
    int add = sAdd;
    int base = blockIdx.x * 1024 + t * 4;
#pragma unroll
    for (int i = 0; i < 4; i++)
        if (base + i < n) off[base + i] += add;
}

// claims slots directly on off: after this kernel off[d] = end pointer.
__global__ void k_fill(const int* __restrict__ src, const int* __restrict__ dst,
                       int* __restrict__ off, int* __restrict__ eidx, int E) {
    int e = blockIdx.x * blockDim.x + threadIdx.x;
    if (e < E) {
        int d = dst[e];
        int p = atomicAdd(&off[d], 1);
        eidx[p] = src[e];
    }
}

// ---------------- aggregation ----------------
// one wave = 4 nodes; quarter-wave (16 lanes) x uint4 (8 feats, 16B) = full
// 256B row per quarter. 8-deep masked chunks. fp32 accumulate.
// off[] holds END pointers (post-fill): base = off[node] - cnt.
__global__ void k_aggregate(const u16* __restrict__ hi_in, const int* __restrict__ eidx,
                            const int* __restrict__ off, const int* __restrict__ deg,
                            u16* __restrict__ mhi, u16* __restrict__ mlo, int n) {
    int wv = blockIdx.x * 4 + (threadIdx.x >> 6);
    int lane = threadIdx.x & 63;
    int quarter = lane >> 4;
    int ql = lane & 15;
    int node = wv * 4 + quarter;
    if (node >= n) return;
    int cnt = deg[node];
    int base = off[node] - cnt;
    const uint4* h4 = (const uint4*)hi_in;  // row = 16 uint4
    float acc[8];
#pragma unroll
    for (int i = 0; i < 8; i++) acc[i] = 0.f;
    for (int j = 0; j < cnt; j += 8) {
        int s[8];
        float m[8];
#pragma unroll
        for (int u = 0; u < 8; u++) {
            int jj = j + u;
            s[u] = eidx[base + (jj < cnt ? jj : 0)];
            m[u] = (jj < cnt) ? 1.f : 0.f;
        }
        uint4 v[8];
#pragma unroll
        for (int u = 0; u < 8; u++) v[u] = h4[(size_t)s[u] * 16 + ql];
#pragma unroll
        for (int u = 0; u < 8; u++) {
            acc[0] = fmaf(m[u], bf2f((u16)(v[u].x & 0xffffu)), acc[0]);
            acc[1] = fmaf(m[u], bf2f((u16)(v[u].x >> 16)), acc[1]);
            acc[2] = fmaf(m[u], bf2f((u16)(v[u].y & 0xffffu)), acc[2]);
            acc[3] = fmaf(m[u], bf2f((u16)(v[u].y >> 16)), acc[3]);
            acc[4] = fmaf(m[u], bf2f((u16)(v[u].z & 0xffffu)), acc[4]);
            acc[5] = fmaf(m[u], bf2f((u16)(v[u].z >> 16)), acc[5]);
            acc[6] = fmaf(m[u], bf2f((u16)(v[u].w & 0xffffu)), acc[6]);
            acc[7] = fmaf(m[u], bf2f((u16)(v[u].w >> 16)), acc[7]);
        }
    }
    float iv = 1.0f / (float)(cnt > 1 ? cnt : 1);
    float a[8], r[8];
#pragma unroll
    for (int i = 0; i < 8; i++) {
        a[i] = acc[i] * iv;
        r[i] = bf2f(f2bf(a[i]));
    }
    uint4 hp, lp;
    hp.x = pack2(a[0], a[1]); hp.y = pack2(a[2], a[3]);
    hp.z = pack2(a[4], a[5]); hp.w = pack2(a[6], a[7]);
    lp.x = pack2(a[0] - r[0], a[1] - r[1]); lp.y = pack2(a[2] - r[2], a[3] - r[3]);
    lp.z = pack2(a[4] - r[4], a[5] - r[5]); lp.w = pack2(a[6] - r[6], a[7] - r[7]);
    ((uint4*)mhi)[(size_t)node * 16 + ql] = hp;
    ((uint4*)mlo)[(size_t)node * 16 + ql] = lp;
}

// ---------------- MFMA GEMM (bf16x3 split), 64x128 tile ----------------
// fout>64 : 2x2 waves, block = 64 rows x 128 cols.
// fout<=64: slim mode, 4 row-wave strips of 16 rows x 48 cols (3 c-tiles).
// LDS tiles [rows][32] u16 = 4 slots of 8 u16 per row.
// Bank fix (rule #21): LDS dest LINEAR for global_load_lds; GLOBAL source
// slot pre-swizzled sg = s ^ ((row>>1)&3); ds_read applies the same XOR ->
// 8 lanes cover all 8 bank-quads (2-way, free) instead of 8-way.
__global__ __launch_bounds__(256) void k_gemm_mfma(
    const u16* __restrict__ Ahi_s, const u16* __restrict__ Alo_s,
    const u16* __restrict__ Ahi_n, const u16* __restrict__ Alo_n,
    const u16* __restrict__ Bthi, const u16* __restrict__ Btlo,
    const float* __restrict__ bias, float* __restrict__ out_f32,
    u16* __restrict__ out_hi, u16* __restrict__ out_lo, int n, int fout, int relu) {
    __shared__ u16 sAhi[64 * 32];
    __shared__ u16 sAlo[64 * 32];
    __shared__ u16 sBhi[128 * 32];
    __shared__ u16 sBlo[128 * 32];

    int t = threadIdx.x;
    int w = t >> 6;
    int lane = t & 63;
    int wr = w >> 1, wc = w & 1;
    size_t row0 = (size_t)blockIdx.x * 64;

    const bool slim = (fout <= 64);
    const int rbase = slim ? (w * 16) : (wr * 32);
    const int nR = slim ? 1 : 2;
    const int nC = slim ? 3 : 4;
    const int cbase = slim ? 0 : (wc * 64);

    f32x4 acc[2][4];
#pragma unroll
    for (int r = 0; r < 2; r++)
#pragma unroll
        for (int c = 0; c < 4; c++) acc[r][c] = (f32x4){0.f, 0.f, 0.f, 0.f};

    int fr = lane & 15;
    int q = lane >> 4;

    for (int kk = 0; kk < 256; kk += 32) {
        const u16* Phi = (kk < 128) ? Ahi_s : Ahi_n;
        const u16* Plo = (kk < 128) ? Alo_s : Alo_n;
        int kc = kk & 127;
        __syncthreads();
        {
            int r = w * 16 + (lane >> 2);
            int s = lane & 3;
            int sg = s ^ ((r >> 1) & 3);  // swizzled source slot
            GLDS16(Phi + (row0 + r) * 128 + kc + sg * 8, &sAhi[r * 32 + s * 8]);
            GLDS16(Plo + (row0 + r) * 128 + kc + sg * 8, &sAlo[r * 32 + s * 8]);
        }
#pragma unroll
        for (int i = 0; i < 2; i++) {
            int c = w * 32 + i * 16 + (lane >> 2);
            int s = lane & 3;
            int sg = s ^ ((c >> 1) & 3);
            GLDS16(Bthi + (size_t)c * 256 + kk + sg * 8, &sBhi[c * 32 + s * 8]);
            GLDS16(Btlo + (size_t)c * 256 + kk + sg * 8, &sBlo[c * 32 + s * 8]);
        }
        __syncthreads();

        bf16x8 a_hi[2], a_lo[2], b_hi[4], b_lo[4];
#pragma unroll
        for (int r = 0; r < 2; r++) {
            if (r >= nR) continue;
            int row = rbase + r * 16 + fr;
            int ad = row * 32 + ((q ^ ((row >> 1) & 3)) << 3);
            a_hi[r] = *(const bf16x8*)&sAhi[ad];
            a_lo[r] = *(const bf16x8*)&sAlo[ad];
        }
#pragma unroll
        for (int c = 0; c < 4; c++) {
            if (c >= nC) continue;
            int col = cbase + c * 16 + fr;
            int ad = col * 32 + ((q ^ ((col >> 1) & 3)) << 3);
            b_hi[c] = *(const bf16x8*)&sBhi[ad];
            b_lo[c] = *(const bf16x8*)&sBlo[ad];
        }
#pragma unroll
        for (int r = 0; r < 2; r++) {
            if (r >= nR) continue;
#pragma unroll
            for (int c = 0; c < 4; c++) {
                if (c >= nC) continue;
                acc[r][c] = __builtin_amdgcn_mfma_f32_16x16x32_bf16(
                    a_hi[r], b_hi[c], acc[r][c], 0, 0, 0);
                acc[r][c] = __builtin_amdgcn_mfma_f32_16x16x32_bf16(
                    a_hi[r], b_lo[c], acc[r][c], 0, 0, 0);
                acc[r][c] = __builtin_amdgcn_mfma_f32_16x16x32_bf16(
                    a_lo[r], b_hi[c], acc[r][c], 0, 0, 0);
            }
        }
    }

    // epilogue: C/D layout col=lane&15, row=quad*4+reg
    int quad = lane >> 4;
    int lcol = lane & 15;
#pragma unroll
    for (int r = 0; r < 2; r++) {
        if (r >= nR) continue;
#pragma unroll
        for (int c = 0; c < 4; c++) {
            if (c >= nC) continue;
            int col = cbase + c * 16 + lcol;
            float bv = (col < fout) ? bias[col] : 0.f;
#pragma unroll
            for (int g = 0; g < 4; g++) {
                size_t row = row0 + rbase + r * 16 + quad * 4 + g;
                if (row >= (size_t)n || col >= fout) continue;
                float v = acc[r][c][g] + bv;
                if (relu) v = v > 0.f ? v : 0.f;
                if (out_f32) out_f32[row * fout + col] = v;
                if (out_hi) {
                    u16 h = f2bf(v);
                    out_hi[row * 128 + col] = h;
                    out_lo[row * 128 + col] = f2bf(v - bf2f(h));
                }
            }
        }
    }
}

extern "C" void kernel_launch(void* const* d_in, const int* in_sizes, int n_in,
                              void* d_out, int out_size, void* d_ws, size_t ws_size,
                              hipStream_t stream) {
    const float* x = (const float*)d_in[0];
    const int* src = (const int*)d_in[1];
    const int* dst = (const int*)d_in[2];
    const float* Ws0 = (const float*)d_in[3];
    const float* Wn0 = (const float*)d_in[4];
    const float* b0 = (const float*)d_in[5];
    const float* Ws1 = (const float*)d_in[6];
    const float* Wn1 = (const float*)d_in[7];
    const float* b1 = (const float*)d_in[8];
    const float* Ws2 = (const float*)d_in[9];
    const float* Wn2 = (const float*)d_in[10];
    const float* b2 = (const float*)d_in[11];
    float* out = (float*)d_out;

    const int N = in_sizes[0] / 128;
    const int E = in_sizes[1];
    const int Npad = ((N + 63) / 64) * 64;

    // ---- workspace layout (bytes) ----
    char* p = (char*)d_ws;
    u16* P0hi = (u16*)p; p += (size_t)Npad * 128 * 2;  // x planes, then h1 planes
    u16* P0lo = (u16*)p; p += (size_t)Npad * 128 * 2;
    u16* P1hi = (u16*)p; p += (size_t)Npad * 128 * 2;  // h0 planes
    u16* P1lo = (u16*)p; p += (size_t)Npad * 128 * 2;
    u16* Mhi = (u16*)p; p += (size_t)Npad * 128 * 2;   // msum planes
    u16* Mlo = (u16*)p; p += (size_t)Npad * 128 * 2;
    u16* Bt = (u16*)p; p += 3 * 2 * 128 * 256 * 2;     // [layer][hi|lo][32768]
    int* deg = (int*)p; p += (size_t)N * 4;
    int* off = (int*)p; p += (size_t)N * 4;
    int* eidx = (int*)p; p += (size_t)E * 4;
    int* bsum = (int*)p;

    const int nPX = N * 32;  // float4s in x
    int nPre = nPX;
    if (E > nPre) nPre = E;
    if (3 * 128 * 256 > nPre) nPre = 3 * 128 * 256;
    const int nbPre = (nPre + THREADS - 1) / THREADS;
    const int nbE = (E + THREADS - 1) / THREADS;
    const int nbScan = (N + 1023) / 1024;
    const int nbAgg = (N + 15) / 16;                   // 4 waves x 4 nodes per block
    const int nbGemm = (N + 63) / 64;

    hipMemsetAsync(deg, 0, (size_t)N * sizeof(int), stream);

    k_preamble<<<nbPre, THREADS, 0, stream>>>(x, P0hi, P0lo, nPX, dst, deg, E,
                                              Ws0, Wn0, Ws1, Wn1, Ws2, Wn2, Bt);
    k_scan_block<<<nbScan, 256, 0, stream>>>(deg, off, bsum, N);
    k_scan_add<<<nbScan, 256, 0, stream>>>(off, bsum, N);
    k_fill<<<nbE, THREADS, 0, stream>>>(src, dst, off, eidx, E);

    // layer 0: x planes -> h0 planes (P1)
    k_aggregate<<<nbAgg, 256, 0, stream>>>(P0hi, eidx, off, deg, Mhi, Mlo, N);
    k_gemm_mfma<<<nbGemm, 256, 0, stream>>>(P0hi, P0lo, Mhi, Mlo,
                                            Bt + 0 * 65536, Bt + 0 * 65536 + 32768, b0,
                                            (float*)nullptr, P1hi, P1lo, N, 128, 1);
    // layer 1: h0 planes -> h1 planes (reuse P0)
    k_aggregate<<<nbAgg, 256, 0, stream>>>(P1hi, eidx, off, deg, Mhi, Mlo, N);
    k_gemm_mfma<<<nbGemm, 256, 0, stream>>>(P1hi, P1lo, Mhi, Mlo,
                                            Bt + 1 * 65536, Bt + 1 * 65536 + 32768, b1,
                                            (float*)nullptr, P0hi, P0lo, N, 128, 1);
    // layer 2: h1 planes -> out (C=47, fp32, no relu) — slim GEMM mode
    k_aggregate<<<nbAgg, 256, 0, stream>>>(P0hi, eidx, off, deg, Mhi, Mlo, N);
    k_gemm_mfma<<<nbGemm, 256, 0, stream>>>(P0hi, P0lo, Mhi, Mlo,
                                            Bt + 2 * 65536, Bt + 2 * 65536 + 32768, b2,
                                            out, (u16*)nullptr, (u16*)nullptr, N, 47, 0);
}